// Round 2
// baseline (293.451 us; speedup 1.0000x reference)
//
#include <hip/hip_runtime.h>
#include <hip/hip_bf16.h>
#include <stdint.h>

#define BATCH 16384
#define D 1024
#define NCLS 1000
#define NPROTO 5000
#define NPROTO_PAD 5120
#define BM 256
#define BN 256
#define BK 32
#define NKT (D / BK)   // 32 K-tiles

typedef float f32x4 __attribute__((ext_vector_type(4)));
typedef __bf16 bf16x8 __attribute__((ext_vector_type(8)));

__device__ __forceinline__ unsigned short f2bf(float x) {
    unsigned u = __float_as_uint(x);
    u += 0x7FFFu + ((u >> 16) & 1u);   // RNE
    return (unsigned short)(u >> 16);
}

// float -> orderable uint (monotone), so atomicMax(uint) == float max
__device__ __forceinline__ unsigned enc_f32(float f) {
    unsigned u = __float_as_uint(f);
    return (u & 0x80000000u) ? ~u : (u | 0x80000000u);
}
__device__ __forceinline__ float dec_f32(unsigned e) {
    return __uint_as_float((e & 0x80000000u) ? (e ^ 0x80000000u) : ~e);
}

// ---------- normalize rows of z and P to bf16, init atomic cells ----------
__global__ __launch_bounds__(256) void k_prep(
        const float* __restrict__ z, const float* __restrict__ P,
        unsigned short* __restrict__ zb, unsigned short* __restrict__ pb,
        unsigned* __restrict__ posU, unsigned* __restrict__ negU) {
    const int b = blockIdx.x;
    const int t = threadIdx.x;
    if (b < BATCH && t == 0) {
        posU[b] = enc_f32(-INFINITY);
        negU[b] = enc_f32(-INFINITY);
    }
    const float* src = nullptr;
    unsigned short* dst;
    if (b < BATCH) {
        src = z + (size_t)b * D;
        dst = zb + (size_t)b * D;
    } else {
        const int r = b - BATCH;
        dst = pb + (size_t)r * D;
        if (r < NPROTO) src = P + (size_t)r * D;
    }
    if (src == nullptr) {                 // padded proto row -> zeros
        ushort4 zr = make_ushort4(0, 0, 0, 0);
        ((ushort4*)dst)[t] = zr;
        return;
    }
    float4 v = ((const float4*)src)[t];   // 256 threads * 4 floats = 1024
    float ss = v.x * v.x + v.y * v.y + v.z * v.z + v.w * v.w;
    #pragma unroll
    for (int off = 32; off >= 1; off >>= 1) ss += __shfl_xor(ss, off);
    __shared__ float red[4];
    const int wave = t >> 6;
    if ((t & 63) == 0) red[wave] = ss;
    __syncthreads();
    const float s = red[0] + red[1] + red[2] + red[3];
    const float inv = 1.0f / fmaxf(sqrtf(s), 1e-12f);
    ushort4 o;
    o.x = f2bf(v.x * inv); o.y = f2bf(v.y * inv);
    o.z = f2bf(v.z * inv); o.w = f2bf(v.w * inv);
    ((ushort4*)dst)[t] = o;
}

// async global->LDS, 16B per lane, dest = wave-uniform base + lane*16
#define GLL(gp, lp) __builtin_amdgcn_global_load_lds( \
    (__attribute__((address_space(1))) const unsigned int*)(const void*)(gp), \
    (__attribute__((address_space(3))) unsigned int*)(void*)(lp), 16, 0, 0)

// ---------- 256x256 bf16 MFMA GEMM, 4-deep pipelined, fused masked row-max --
__global__ __launch_bounds__(512, 2) void k_gemm(
        const unsigned short* __restrict__ zb,
        const unsigned short* __restrict__ pb,
        const int* __restrict__ y,
        unsigned* __restrict__ posU, unsigned* __restrict__ negU) {
    // fragment-packed LDS: [slot][A=0/B=1][frag 0..15][lane 0..63][8 bf16]
    // ds_read for frag f = base + lane*16  -> stride-1, conflict-free
    __shared__ __align__(16) unsigned short L[4][2][16][64][8];   // 128 KiB

    const int t = threadIdx.x;
    const int w = t >> 6;                    // wave 0..7
    const int lane = t & 63;
    const int lm = lane & 15, lk = lane >> 4;
    const int wm = w >> 2, wn = w & 3;       // 2(M) x 4(N) wave grid

    const int rowbase = blockIdx.y * BM;
    const int colbase = blockIdx.x * BN;

    // pre-swizzled global sources: lane supplies the element that belongs at
    // LDS slot (frag, lane): row = frag*16 + lm, k = lk*8 .. +8
    const unsigned short* gA0 = zb + (size_t)(rowbase + w * 16 + lm) * D + lk * 8;
    const unsigned short* gA1 = gA0 + (size_t)128 * D;
    const unsigned short* gB0 = pb + (size_t)(colbase + w * 16 + lm) * D + lk * 8;
    const unsigned short* gB1 = gB0 + (size_t)128 * D;

#define STAGE(kt) do {                                   \
    const int s_ = (kt) & 3;                             \
    const int ko_ = (kt) * BK;                           \
    GLL(gA0 + ko_, &L[s_][0][w][0][0]);                  \
    GLL(gA1 + ko_, &L[s_][0][w + 8][0][0]);              \
    GLL(gB0 + ko_, &L[s_][1][w][0][0]);                  \
    GLL(gB1 + ko_, &L[s_][1][w + 8][0][0]);              \
} while (0)

    f32x4 acc[8][4];
    #pragma unroll
    for (int i = 0; i < 8; ++i)
        #pragma unroll
        for (int j = 0; j < 4; ++j) {
            f32x4 z4 = {0.0f, 0.0f, 0.0f, 0.0f};
            acc[i][j] = z4;
        }

    // prologue: 3 K-tiles in flight (12 loads/thread)
    STAGE(0); STAGE(1); STAGE(2);

// one phase per K-tile: counted vmcnt (never 0 in steady state), ONE barrier,
// 12 ds_read_b128 + 4 global_load_lds + 32 MFMA. stage(i+3) targets slot
// (i-1)&3 whose reads completed before barrier_i (lgkmcnt(0) precedes it).
#define BODY(i, VMC, DO_STAGE) do {                                           \
    asm volatile("s_waitcnt vmcnt(" #VMC ")" ::: "memory");                   \
    asm volatile("s_barrier" ::: "memory");                                   \
    const int s_ = (i) & 3;                                                   \
    bf16x8 a[8], b[4];                                                        \
    _Pragma("unroll")                                                         \
    for (int mi = 0; mi < 8; ++mi)                                            \
        a[mi] = *(const bf16x8*)&L[s_][0][wm * 8 + mi][lane][0];              \
    _Pragma("unroll")                                                         \
    for (int ni = 0; ni < 4; ++ni)                                            \
        b[ni] = *(const bf16x8*)&L[s_][1][wn * 4 + ni][lane][0];              \
    if (DO_STAGE) STAGE((i) + 3);                                             \
    __builtin_amdgcn_s_setprio(1);                                            \
    _Pragma("unroll")                                                         \
    for (int mi = 0; mi < 8; ++mi)                                            \
        _Pragma("unroll")                                                     \
        for (int ni = 0; ni < 4; ++ni)                                        \
            acc[mi][ni] = __builtin_amdgcn_mfma_f32_16x16x32_bf16(            \
                a[mi], b[ni], acc[mi][ni], 0, 0, 0);                          \
    __builtin_amdgcn_s_setprio(0);                                            \
    asm volatile("s_waitcnt lgkmcnt(0)" ::: "memory");                        \
} while (0)

    #pragma unroll 1
    for (int i = 0; i < NKT - 3; ++i) BODY(i, 8, 1);
    BODY(NKT - 3, 8, 0);
    BODY(NKT - 2, 4, 0);
    BODY(NKT - 1, 0, 0);

    // fused epilogue: masked pos/neg max per output row
    // C/D layout: col = lane&15 (proto), row = (lane>>4)*4 + reg (batch)
    const int col00 = colbase + wn * 64 + lm;
    #pragma unroll
    for (int mi = 0; mi < 8; ++mi) {
        #pragma unroll
        for (int r = 0; r < 4; ++r) {
            const int row_g = rowbase + wm * 128 + mi * 16 + lk * 4 + r;
            const int yv = y[row_g];
            float pm = -INFINITY, nm = -INFINITY;
            #pragma unroll
            for (int ni = 0; ni < 4; ++ni) {
                const int col_g = col00 + ni * 16;
                const float v = acc[mi][ni][r];
                const bool same = (col_g / 5) == yv;   // same => col_g < 5000
                if (same) pm = fmaxf(pm, v);
                else if (col_g < NPROTO) nm = fmaxf(nm, v);
            }
            #pragma unroll
            for (int off = 1; off < 16; off <<= 1) {
                pm = fmaxf(pm, __shfl_xor(pm, off));
                nm = fmaxf(nm, __shfl_xor(nm, off));
            }
            if (lm == 0) {
                if (pm > -INFINITY) atomicMax(&posU[row_g], enc_f32(pm));
                if (nm > -INFINITY) atomicMax(&negU[row_g], enc_f32(nm));
            }
        }
    }
#undef BODY
#undef STAGE
}

// ---------- decode to output ----------
__global__ __launch_bounds__(256) void k_finish(
        const unsigned* __restrict__ posU, const unsigned* __restrict__ negU,
        float* __restrict__ out) {
    const int i = blockIdx.x * 256 + threadIdx.x;
    if (i < BATCH) {
        out[i] = dec_f32(posU[i]);
        out[BATCH + i] = dec_f32(negU[i]);
    }
}

extern "C" void kernel_launch(void* const* d_in, const int* in_sizes, int n_in,
                              void* d_out, int out_size, void* d_ws, size_t ws_size,
                              hipStream_t stream) {
    const float* z = (const float*)d_in[0];
    const int*   y = (const int*)d_in[1];
    const float* P = (const float*)d_in[2];

    // ws layout: zb 32MB | pb 10MB | posU 64KB | negU 64KB  (~42.2 MB)
    unsigned short* zb = (unsigned short*)d_ws;
    unsigned short* pb = zb + (size_t)BATCH * D;
    unsigned* posU = (unsigned*)(pb + (size_t)NPROTO_PAD * D);
    unsigned* negU = posU + BATCH;
    float* out = (float*)d_out;

    k_prep<<<BATCH + NPROTO_PAD, 256, 0, stream>>>(z, P, zb, pb, posU, negU);
    dim3 grid(NPROTO_PAD / BN, BATCH / BM);
    k_gemm<<<grid, 512, 0, stream>>>(zb, pb, y, posU, negU);
    k_finish<<<BATCH / 256, 256, 0, stream>>>(posU, negU, out);
}